// Round 11
// baseline (585.779 us; speedup 1.0000x reference)
//
#include <hip/hip_runtime.h>
#include <math.h>

constexpr int NB = 8, NC = 256, NE = 512, NH = 64, NW = 64, NHW = NH * NW;
constexpr int STEPS = 6;

typedef short bfrag8 __attribute__((ext_vector_type(8)));   // 8 bf16 in 4 VGPRs
typedef float f32x4 __attribute__((ext_vector_type(4)));

__device__ __forceinline__ float sigm_(float x) { return 1.f / (1.f + expf(-x)); }
// tanh-form GELU, overflow-safe: x * sigmoid(1.5957691(x + 0.044715 x^3))
__device__ __forceinline__ float gelu_(float x) {
    const float t2 = fmaf(0.0713548162f * x, x * x, 1.5957691216f * x);
    return x / (1.f + __expf(-t2));
}
__device__ __forceinline__ ushort f2bf(float f) {
    unsigned u = __builtin_bit_cast(unsigned, f);
    unsigned r = (u + 0x7fffu + ((u >> 16) & 1u)) >> 16;   // RNE
    return (ushort)r;
}
__device__ __forceinline__ float bf2f(ushort us) {
    return __builtin_bit_cast(float, (unsigned)us << 16);
}
__device__ __forceinline__ void gload16(const void* g, void* l) {
    __builtin_amdgcn_global_load_lds((const __attribute__((address_space(1))) void*)g,
                                     (__attribute__((address_space(3))) void*)l, 16, 0, 0);
}

// ---------- prologue: bf16 weights (w1t, w2t, gate-transposed) + coefficients ----------
__global__ void wt_kernel(const float* __restrict__ w1, const float* __restrict__ w2,
                          const float* __restrict__ dlog,
                          const float* __restrict__ wf, const float* __restrict__ wi,
                          const float* __restrict__ wc,
                          ushort* __restrict__ w1t, ushort* __restrict__ w2t,
                          float* __restrict__ dcoef, ushort* __restrict__ wgt) {
    const int bid = blockIdx.x, tid = threadIdx.x;
    if (bid < NE) {                       // w1t[e][c] = w1[c][e]
        w1t[bid * NC + tid] = f2bf(w1[(size_t)tid * NE + bid]);
    } else if (bid < NE + NC) {           // w2t[c][e] = w2[e][c]
        const int c = bid - NE;
        for (int e = tid; e < NE; e += 256)
            w2t[c * NE + e] = f2bf(w2[(size_t)e * NC + c]);
    } else if (bid == NE + NC) {
#pragma unroll
        for (int i = 0; i < 3; ++i)
            dcoef[i * NC + tid] = 0.25f * sigm_(dlog[i * NC + tid]);
    } else {                              // gate weights transposed: wgt[g][c][k] = W_g[k][c]
        const int j = bid - (NE + NC + 1);     // 0..767
        const int g = j >> 8, c = j & 255, k = tid;
        const float* src = (g == 0) ? wf : (g == 1) ? wi : wc;
        wgt[(((size_t)g * NC + c) << 8) + k] = f2bf(src[(size_t)k * NC + c]);
    }
}

// ---------- prologue: forcing -> bf16 ----------
__global__ void fconv_kernel(const float* __restrict__ fin, ushort* __restrict__ fout) {
    const size_t i8 = ((size_t)blockIdx.x * 256 + threadIdx.x) * 8;
    const float4 a = *reinterpret_cast<const float4*>(fin + i8);
    const float4 b = *reinterpret_cast<const float4*>(fin + i8 + 4);
    uint4 o;
    o.x = (unsigned)f2bf(a.x) | ((unsigned)f2bf(a.y) << 16);
    o.y = (unsigned)f2bf(a.z) | ((unsigned)f2bf(a.w) << 16);
    o.z = (unsigned)f2bf(b.x) | ((unsigned)f2bf(b.y) << 16);
    o.w = (unsigned)f2bf(b.z) | ((unsigned)f2bf(b.w) << 16);
    *reinterpret_cast<uint4*>(fout + i8) = o;
}

// ---------- prologue: initial per-row channel sums from u0 ----------
__global__ __launch_bounds__(256) void rs0_kernel(const float* __restrict__ u,
                                                  float* __restrict__ rowsums) {
    const int b = blockIdx.x >> 6, y = blockIdx.x & 63;
    const int c = threadIdx.x;
    const float* rp = u + ((size_t)b * NC + c) * NHW + (size_t)y * NW;
    float s = 0.f;
#pragma unroll
    for (int i = 0; i < 16; ++i) {
        const float4 v = *reinterpret_cast<const float4*>(rp + i * 4);
        s += (v.x + v.y) + (v.z + v.w);
    }
    rowsums[((size_t)b * 64 + y) * NC + c] = s;
}

// ---------- fused step: GEMMs + in-kernel gates + stencil + Euler + RMSNorm ----------
__global__ __launch_bounds__(512, 4) void step_kernel(
    const ushort* __restrict__ w1t, const ushort* __restrict__ w2t,
    const float* __restrict__ b1, const float* __restrict__ b2,
    const float* __restrict__ uin, const ushort* __restrict__ forc,
    const float* __restrict__ dcoef, const ushort* __restrict__ wgt,
    const float* __restrict__ bfv, const float* __restrict__ biv,
    const float* __restrict__ bcv, const float* __restrict__ hprev,
    float* __restrict__ hnext, const float* __restrict__ rs_in,
    float* __restrict__ rs_out, const float* __restrict__ nsc,
    const float* __restrict__ p_logdt, const float* __restrict__ p_am,
    const float* __restrict__ p_af, const int do_norm, const int first,
    float* __restrict__ uout) {
    __shared__ __align__(16) char pool[79872];
    ushort* Xs  = (ushort*)pool;                 // [64px][256c] swizzled      (32KB)
    ushort* WAu = (ushort*)(pool + 32768);       // w1 chunk [32e][256c] swz   (16KB)
    ushort* WBu = (ushort*)(pool + 49152);       // w2 chunk [256c][32e] swz   (16KB)
    ushort* Hsu = (ushort*)(pool + 65536);       // Hs dbuf 2x[64px][40e-pad]  (10KB)
    float* gsp  = (float*)(pool + 75776);        // [256] pooled (psum half 0)
    float* gex  = (float*)(pool + 76800);        // [256] psum half 1 / gate-i
    float* hseg = (float*)(pool + 77824);        // [256] am*h_t

    const int tid = threadIdx.x;
    const int wv = tid >> 6, lane = tid & 63;
    const int r16 = lane & 15, kg = lane >> 4;
    const int work = (blockIdx.x & 7) * 64 + (blockIdx.x >> 3);   // XCD swizzle
    const int b = work >> 6, y = work & 63;

    const float am = p_am[0];
    const float* ub = uin + (size_t)b * NC * NHW;
    const float* uyb = ub + (size_t)y * NW;

    // ---- stage w1 chunk 0 (gload) + Xs from u row y (reg 4x4 transpose -> ds_write) ----
#pragma unroll
    for (int i = 0; i < 2; ++i) {
        const int idx = i * 512 + tid, row = idx >> 5, s = idx & 31;
        gload16(w1t + (size_t)row * NC + ((s ^ (row & 7)) << 3), WAu + idx * 8);
    }
#pragma unroll
    for (int tt = 0; tt < 2; ++tt) {
        const int id = tt * 512 + tid;
        const int pg_ = id & 15, cg_ = id >> 4;       // cg_ 0..63
        const int px0 = pg_ * 4, c0 = cg_ * 4;
        const float4 r0 = *(const float4*)(uyb + (size_t)(c0 + 0) * NHW + px0);
        const float4 r1 = *(const float4*)(uyb + (size_t)(c0 + 1) * NHW + px0);
        const float4 r2 = *(const float4*)(uyb + (size_t)(c0 + 2) * NHW + px0);
        const float4 r3 = *(const float4*)(uyb + (size_t)(c0 + 3) * NHW + px0);
        const int slot = c0 >> 3, sub = c0 & 7;       // sub in {0,4}
        const float a0[4] = {r0.x, r0.y, r0.z, r0.w};
        const float a1[4] = {r1.x, r1.y, r1.z, r1.w};
        const float a2[4] = {r2.x, r2.y, r2.z, r2.w};
        const float a3[4] = {r3.x, r3.y, r3.z, r3.w};
#pragma unroll
        for (int i2 = 0; i2 < 4; ++i2) {
            const int px = px0 + i2;
            ushort4 xv;
            xv.x = f2bf(a0[i2]);
            xv.y = f2bf(a1[i2]);
            xv.z = f2bf(a2[i2]);
            xv.w = f2bf(a3[i2]);
            *(ushort4*)(Xs + px * 256 + ((slot ^ (px & 7)) << 3) + sub) = xv;
        }
    }
    // pooled partial sums (32 rows each half)
    {
        const int gc = tid & 255, half = tid >> 8;
        const float* rs = rs_in + ((size_t)b * 64 + half * 32) * NC + gc;
        float s = 0.f;
#pragma unroll 8
        for (int yy = 0; yy < 32; ++yy) s += rs[yy * NC];
        (half ? gex : gsp)[gc] = s;
    }

    f32x4 acc2[2][4];   // [ct][p]; wave's c-slice = wv*32
#pragma unroll
    for (int ct = 0; ct < 2; ++ct)
#pragma unroll
        for (int p = 0; p < 4; ++p) acc2[ct][p] = (f32x4){0.f, 0.f, 0.f, 0.f};

    const int eh = wv >> 2, pq = wv & 3;   // GEMM1 wave role: e-half, px-quadrant
    __syncthreads();                       // A: Xs + psum visible; WA(0) drained

    // ---- hoist X fragments to registers (invariant across e-chunks) ----
    bfrag8 xf[8];
    {
        const int rB = pq * 16 + r16;
#pragma unroll
        for (int kk = 0; kk < 8; ++kk) {
            const int g = kk * 4 + kg;
            xf[kk] = *(const bfrag8*)(Xs + rB * 256 + ((g ^ (rB & 7)) << 3));
        }
    }
    if (tid < 256) gsp[tid] = (gsp[tid] + gex[tid]) * (1.f / 4096.f);
    __syncthreads();                       // B: sp(pooled) ready

    // ---- in-block gates: f/i gemv (split halves), c gemv (lower half) ----
    float gfv = 0.f, ccv = 0.f;
    {
        const int gc = tid & 255, g1 = tid >> 8;          // 0:f  1:i
        const ushort* wrow = wgt + (((size_t)g1 * NC + gc) << 8);
        float a0 = 0.f, a1 = 0.f;
#pragma unroll 4
        for (int k8 = 0; k8 < 256; k8 += 8) {
            const uint4 wv4 = *(const uint4*)(wrow + k8);
            a0 = fmaf(gsp[k8 + 0], bf2f((ushort)(wv4.x & 0xffff)), a0);
            a1 = fmaf(gsp[k8 + 1], bf2f((ushort)(wv4.x >> 16)), a1);
            a0 = fmaf(gsp[k8 + 2], bf2f((ushort)(wv4.y & 0xffff)), a0);
            a1 = fmaf(gsp[k8 + 3], bf2f((ushort)(wv4.y >> 16)), a1);
            a0 = fmaf(gsp[k8 + 4], bf2f((ushort)(wv4.z & 0xffff)), a0);
            a1 = fmaf(gsp[k8 + 5], bf2f((ushort)(wv4.z >> 16)), a1);
            a0 = fmaf(gsp[k8 + 6], bf2f((ushort)(wv4.w & 0xffff)), a0);
            a1 = fmaf(gsp[k8 + 7], bf2f((ushort)(wv4.w >> 16)), a1);
        }
        const float av = (a0 + a1) + (g1 == 0 ? bfv[gc] : biv[gc]);
        if (g1 == 0) gfv = sigm_(av);
        else gex[gc] = sigm_(av);
        if (tid < 256) {                                  // c-gate
            const ushort* wrow2 = wgt + (((size_t)2 * NC + gc) << 8);
            float c0 = 0.f, c1 = 0.f;
#pragma unroll 4
            for (int k8 = 0; k8 < 256; k8 += 8) {
                const uint4 wv4 = *(const uint4*)(wrow2 + k8);
                c0 = fmaf(gsp[k8 + 0], bf2f((ushort)(wv4.x & 0xffff)), c0);
                c1 = fmaf(gsp[k8 + 1], bf2f((ushort)(wv4.x >> 16)), c1);
                c0 = fmaf(gsp[k8 + 2], bf2f((ushort)(wv4.y & 0xffff)), c0);
                c1 = fmaf(gsp[k8 + 3], bf2f((ushort)(wv4.y >> 16)), c1);
                c0 = fmaf(gsp[k8 + 4], bf2f((ushort)(wv4.z & 0xffff)), c0);
                c1 = fmaf(gsp[k8 + 5], bf2f((ushort)(wv4.z >> 16)), c1);
                c0 = fmaf(gsp[k8 + 6], bf2f((ushort)(wv4.w & 0xffff)), c0);
                c1 = fmaf(gsp[k8 + 7], bf2f((ushort)(wv4.w >> 16)), c1);
            }
            ccv = tanhf((c0 + c1) + bcv[gc]);
        }
    }
    __syncthreads();                       // C: gate-i (gex) visible
    if (tid < 256) {
        const int gc = tid;
        const float hp = first ? 0.f : hprev[b * NC + gc];
        const float h = hp * gfv + gex[gc] * ccv;
        hseg[gc] = am * h;
        if (y == 0) hnext[b * NC + gc] = h;
    }

    // ---- GEMM loop: pipelined 32-wide e-chunks ----
    for (int ec = 0; ec < 16; ++ec) {
        // stage w2 chunk ec -> WB: LINEAR dest, inverse-swz SOURCE (rule #21)
#pragma unroll
        for (int i = 0; i < 2; ++i) {
            const int idx = i * 512 + tid, row = idx >> 2, s = idx & 3;
            const int sc = (s ^ ((row >> 1) & 3)) << 3;
            gload16(w2t + (size_t)row * NE + ec * 32 + sc, WBu + idx * 8);
        }
        // GEMM1: D1[e][px] from WA x xf(regs)
        f32x4 acc1 = (f32x4){0.f, 0.f, 0.f, 0.f};
        const int rA = eh * 16 + r16;
#pragma unroll
        for (int kk = 0; kk < 8; ++kk) {
            const int g = kk * 4 + kg;
            const bfrag8 a = *(const bfrag8*)(WAu + rA * 256 + ((g ^ (rA & 7)) << 3));
            acc1 = __builtin_amdgcn_mfma_f32_16x16x32_bf16(a, xf[kk], acc1, 0, 0, 0);
        }
        // GELU -> Hs[ec&1]
        ushort* Hc = Hsu + (ec & 1) * 2560;
        {
            const int el = eh * 16 + kg * 4;
            const float4 b1v = *(const float4*)(b1 + ec * 32 + el);
            ushort4 hv;
            hv.x = f2bf(gelu_(acc1[0] + b1v.x));
            hv.y = f2bf(gelu_(acc1[1] + b1v.y));
            hv.z = f2bf(gelu_(acc1[2] + b1v.z));
            hv.w = f2bf(gelu_(acc1[3] + b1v.w));
            *(ushort4*)(Hc + (pq * 16 + r16) * 40 + el) = hv;
        }
        __syncthreads();   // B1: WB drained (hidden under G1+GELU); Hs visible; WA free
        if (ec < 15) {     // stage w1 chunk ec+1 -> WA (drains at B2, hidden under G2)
#pragma unroll
            for (int i = 0; i < 2; ++i) {
                const int idx = i * 512 + tid, row = idx >> 5, s = idx & 31;
                gload16(w1t + (size_t)((ec + 1) * 32 + row) * NC + ((s ^ (row & 7)) << 3),
                        WAu + idx * 8);
            }
        }
        // GEMM2: react[c][px] += WB x Hs
#pragma unroll
        for (int ct = 0; ct < 2; ++ct) {
            const int rowA = wv * 32 + ct * 16 + r16;
            const bfrag8 a2 = *(const bfrag8*)(WBu + rowA * 32 + ((kg ^ ((rowA >> 1) & 3)) << 3));
#pragma unroll
            for (int p = 0; p < 4; ++p) {
                const bfrag8 bf2 = *(const bfrag8*)(Hc + (p * 16 + r16) * 40 + kg * 8);
                acc2[ct][p] = __builtin_amdgcn_mfma_f32_16x16x32_bf16(a2, bf2, acc2[ct][p], 0, 0, 0);
            }
        }
        __syncthreads();   // B2: WA(ec+1) drained; WB free for next stage
    }

    // ---- epilogue: reflect-padded window stencil ----
    float* trh = (float*)pool;                     // [128][69] f32 (half of c)
    float* su  = (float*)(pool + 35328);           // [128][72] f32, data at cols 4..67
    const int eg2 = tid >> 4, pg = tid & 15, x0p = pg * 4;
    const float dt = fminf(fmaxf(expf(p_logdt[0]), 0.01f), 0.3f);
    const float afc = p_af[0];
    const ushort* frow = forc + (size_t)b * NC * NHW + (size_t)y * NW;

    float unew[2][4][4];   // [h2][jc][ip]

#pragma unroll
    for (int h2 = 0; h2 < 2; ++h2) {
        __syncthreads();   // GEMM done / prev-half trh+su reads done
        if ((wv >> 2) == h2) {
#pragma unroll
            for (int ct = 0; ct < 2; ++ct)
#pragma unroll
                for (int p = 0; p < 4; ++p)
#pragma unroll
                    for (int j = 0; j < 4; ++j)
                        trh[((wv & 3) * 32 + ct * 16 + kg * 4 + j) * 69 + p * 16 + r16] =
                            acc2[ct][p][j];
        }
#pragma unroll
        for (int i = 0; i < 4; ++i) {   // stage u_old half [128c][64px] at col offset 4
            const int idx = i * 512 + tid;
            const int r = idx >> 4, q = (idx & 15) * 4;
            *(float4*)&su[r * 72 + 4 + q] =
                *(const float4*)(ub + (size_t)(h2 * 128 + r) * NHW + (size_t)y * NW + q);
        }
        if (tid < 256) {                 // fill reflect pads from global (no extra barrier)
            const int r = tid >> 1, side = tid & 1;
            const float* gp = ub + (size_t)(h2 * 128 + r) * NHW + (size_t)y * NW;
            float* sr = &su[r * 72];
            if (side == 0) { sr[0] = gp[4]; sr[1] = gp[3]; sr[2] = gp[2]; sr[3] = gp[1]; }
            else { sr[68] = gp[62]; sr[69] = gp[61]; sr[70] = gp[60]; sr[71] = gp[59]; }
        }
        __syncthreads();   // trh + su(+pads) ready
#pragma unroll
        for (int jc = 0; jc < 4; ++jc) {
            const int crel = eg2 * 4 + jc;
            const int c = h2 * 128 + crel;
            const float co0 = dcoef[c];
            const float co1 = dcoef[NC + c];
            const float co2 = dcoef[2 * NC + c];
            const float hterm = hseg[c];
            const float b2v = b2[c];
            const float* up = ub + (size_t)c * NHW;

            float ym[6][4];
            const int dy[6] = {-1, 1, -2, 2, -4, 4};
#pragma unroll
            for (int n = 0; n < 6; ++n) {
                int ry = y + dy[n];
                ry = ry < 0 ? -ry : (ry > 63 ? 126 - ry : ry);
                const float4 t = *reinterpret_cast<const float4*>(up + (size_t)ry * NW + x0p);
                ym[n][0] = t.x; ym[n][1] = t.y; ym[n][2] = t.z; ym[n][3] = t.w;
            }
            const uint2 fr = *reinterpret_cast<const uint2*>(frow + (size_t)c * NHW + x0p);
            float fv[4];
            fv[0] = bf2f((ushort)(fr.x & 0xffff));
            fv[1] = bf2f((ushort)(fr.x >> 16));
            fv[2] = bf2f((ushort)(fr.y & 0xffff));
            fv[3] = bf2f((ushort)(fr.y >> 16));
            const f32x4 rv = *reinterpret_cast<const f32x4*>(&trh[crel * 69 + x0p]);
            // 12-float reflect window: w[k] = v[x0p-4+k], v = reflected row
            const f32x4 wm = *reinterpret_cast<const f32x4*>(&su[crel * 72 + pg * 4]);
            const f32x4 wc4 = *reinterpret_cast<const f32x4*>(&su[crel * 72 + 4 + pg * 4]);
            const f32x4 wp = *reinterpret_cast<const f32x4*>(&su[crel * 72 + 8 + pg * 4]);
            const float w[12] = {wm[0], wm[1], wm[2], wm[3],
                                 wc4[0], wc4[1], wc4[2], wc4[3],
                                 wp[0], wp[1], wp[2], wp[3]};
#pragma unroll
            for (int ip = 0; ip < 4; ++ip) {
                const float uc = w[4 + ip];
                float dsum;
                float lap = (w[3 + ip] + w[5 + ip]) + (ym[0][ip] + ym[1][ip]) - 4.f * uc;
                dsum = co0 * lap;
                lap = (w[2 + ip] + w[6 + ip]) + (ym[2][ip] + ym[3][ip]) - 4.f * uc;
                dsum = fmaf(co1, lap, dsum);
                lap = (w[ip] + w[8 + ip]) + (ym[4][ip] + ym[5][ip]) - 4.f * uc;
                dsum = fmaf(co2, lap, dsum);

                const float du_ = dsum + rv[ip] + b2v + hterm + afc * fv[ip];
                unew[h2][jc][ip] = uc + dt * du_;
            }
        }
    }
    __syncthreads();   // trh/su dead

    // ---- RMSNorm ----
    float* redc   = (float*)(pool + 35328);        // [32][69] (overlays su)
    float* inv64p = (float*)(pool + 73728);        // [64] (dead Hsu tail)
    if (do_norm) {
        float ps[4] = {0.f, 0.f, 0.f, 0.f};
#pragma unroll
        for (int h2 = 0; h2 < 2; ++h2)
#pragma unroll
            for (int jc = 0; jc < 4; ++jc)
#pragma unroll
                for (int ip = 0; ip < 4; ++ip)
                    ps[ip] = fmaf(unew[h2][jc][ip], unew[h2][jc][ip], ps[ip]);
        *reinterpret_cast<f32x4*>(&redc[eg2 * 69 + x0p]) = (f32x4){ps[0], ps[1], ps[2], ps[3]};
        __syncthreads();
        if (tid < 64) {
            float s = 0.f;
#pragma unroll
            for (int g = 0; g < 32; ++g) s += redc[g * 69 + tid];
            inv64p[tid] = 1.f / (sqrtf(s) * 0.0625f + 1e-6f);
        }
    }
    __syncthreads();   // inv64 ready; redc region free for sums

    // ---- store u_new (fp32, channel-major) + rowsums(next) ----
    float* sums = (float*)(pool + 35328);          // [256][17]
    float* uob = uout + (size_t)b * NC * NHW + (size_t)y * NW;
#pragma unroll
    for (int h2 = 0; h2 < 2; ++h2) {
#pragma unroll
        for (int jc = 0; jc < 4; ++jc) {
            const int c = h2 * 128 + eg2 * 4 + jc;
            const float ns = do_norm ? nsc[c] : 1.f;
            float vv[4];
#pragma unroll
            for (int ip = 0; ip < 4; ++ip) {
                float v = unew[h2][jc][ip];
                if (do_norm) v *= inv64p[x0p + ip] * ns;
                vv[ip] = v;
            }
            float4 o; o.x = vv[0]; o.y = vv[1]; o.z = vv[2]; o.w = vv[3];
            *reinterpret_cast<float4*>(uob + (size_t)c * NHW + x0p) = o;
            sums[c * 17 + pg] = (vv[0] + vv[1]) + (vv[2] + vv[3]);
        }
    }
    __syncthreads();   // sums ready
    if (tid < 256) {
        float s = 0.f;
#pragma unroll
        for (int g = 0; g < 16; ++g) s += sums[tid * 17 + g];
        rs_out[((size_t)b * 64 + y) * NC + tid] = s;
    }
}

extern "C" void kernel_launch(void* const* d_in, const int* in_sizes, int n_in,
                              void* d_out, int out_size, void* d_ws, size_t ws_size,
                              hipStream_t stream) {
    (void)in_sizes; (void)n_in; (void)out_size; (void)ws_size;
    const float* u0      = (const float*)d_in[0];
    const float* forcing = (const float*)d_in[1];
    const float* dlog    = (const float*)d_in[2];
    const float* w1      = (const float*)d_in[3];
    const float* b1      = (const float*)d_in[4];
    const float* w2      = (const float*)d_in[5];
    const float* b2      = (const float*)d_in[6];
    const float* wf      = (const float*)d_in[7];
    const float* bfv     = (const float*)d_in[8];
    const float* wi      = (const float*)d_in[9];
    const float* biv     = (const float*)d_in[10];
    const float* wc      = (const float*)d_in[11];
    const float* bcv     = (const float*)d_in[12];
    const float* nsc     = (const float*)d_in[13];
    const float* p_logdt = (const float*)d_in[14];
    const float* p_am    = (const float*)d_in[15];
    const float* p_af    = (const float*)d_in[16];

    float* uout = (float*)d_out;

    char* w = (char*)d_ws;
    float*  uA     = (float*)w;   w += (size_t)NB * NC * NHW * 4;   // 33.5 MB
    ushort* forc   = (ushort*)w;  w += (size_t)NB * NC * NHW * 2;   // 16.8 MB
    ushort* w1t    = (ushort*)w;  w += (size_t)NE * NC * 2;
    ushort* w2t    = (ushort*)w;  w += (size_t)NC * NE * 2;
    ushort* wgt    = (ushort*)w;  w += (size_t)3 * NC * NC * 2;     // 384 KB
    float* rsA     = (float*)w;   w += (size_t)NB * NH * NC * 4;    // 512 KB
    float* rsB     = (float*)w;   w += (size_t)NB * NH * NC * 4;    // 512 KB
    float* hA      = (float*)w;   w += (size_t)NB * NC * 4;
    float* hB      = (float*)w;   w += (size_t)NB * NC * 4;
    float* dcoef   = (float*)w;   w += (size_t)3 * NC * 4;

    wt_kernel<<<NE + NC + 1 + 3 * NC, 256, 0, stream>>>(w1, w2, dlog, wf, wi, wc,
                                                        w1t, w2t, dcoef, wgt);
    fconv_kernel<<<4096, 256, 0, stream>>>(forcing, forc);
    rs0_kernel<<<NB * NH, 256, 0, stream>>>(u0, rsA);

    const float* src = u0;
    const float* rs_in = rsA;
    float* rs_out = rsB;
    float* hbufs[2] = {hA, hB};
    for (int t = 0; t < STEPS; ++t) {
        float* dst = (t & 1) ? uout : uA;    // t=5 -> uout
        const float* hp = hbufs[t & 1];
        float* hn = hbufs[(t + 1) & 1];
        step_kernel<<<NB * NH, 512, 0, stream>>>(w1t, w2t, b1, b2, src, forc, dcoef,
                                                 wgt, bfv, biv, bcv, hp, hn,
                                                 rs_in, rs_out, nsc, p_logdt, p_am, p_af,
                                                 ((t + 1) % 2) == 0, t == 0, dst);
        src = dst;
        const float* tmp = rs_in; rs_in = rs_out; rs_out = (float*)tmp;
    }
}

// Round 14
// 565.294 us; speedup vs baseline: 1.0362x; 1.0362x over previous
//
#include <hip/hip_runtime.h>
#include <math.h>

constexpr int NB = 8, NC = 256, NE = 512, NH = 64, NW = 64, NHW = NH * NW;
constexpr int STEPS = 6;

typedef short bfrag8 __attribute__((ext_vector_type(8)));   // 8 bf16 in 4 VGPRs
typedef float f32x4 __attribute__((ext_vector_type(4)));

__device__ __forceinline__ float sigm_(float x) { return 1.f / (1.f + expf(-x)); }
// tanh-form GELU, overflow-safe: x * sigmoid(1.5957691(x + 0.044715 x^3))
__device__ __forceinline__ float gelu_(float x) {
    const float t2 = fmaf(0.0713548162f * x, x * x, 1.5957691216f * x);
    return x / (1.f + __expf(-t2));
}
__device__ __forceinline__ ushort f2bf(float f) {
    unsigned u = __builtin_bit_cast(unsigned, f);
    unsigned r = (u + 0x7fffu + ((u >> 16) & 1u)) >> 16;   // RNE
    return (ushort)r;
}
__device__ __forceinline__ float bf2f(ushort us) {
    return __builtin_bit_cast(float, (unsigned)us << 16);
}
__device__ __forceinline__ void gload16(const void* g, void* l) {
    __builtin_amdgcn_global_load_lds((const __attribute__((address_space(1))) void*)g,
                                     (__attribute__((address_space(3))) void*)l, 16, 0, 0);
}

// ---------- prologue: bf16 weights (w1t, w2t, gates) + stencil coefficients ----------
__global__ void wt_kernel(const float* __restrict__ w1, const float* __restrict__ w2,
                          const float* __restrict__ dlog,
                          const float* __restrict__ wf, const float* __restrict__ wi,
                          const float* __restrict__ wc,
                          ushort* __restrict__ w1t, ushort* __restrict__ w2t,
                          float* __restrict__ dcoef, ushort* __restrict__ wgb) {
    const int bid = blockIdx.x, tid = threadIdx.x;
    if (bid < NE) {                       // w1t[e][c] = w1[c][e]
        w1t[bid * NC + tid] = f2bf(w1[(size_t)tid * NE + bid]);
    } else if (bid < NE + NC) {           // w2t[c][e] = w2[e][c]
        const int c = bid - NE;
        for (int e = tid; e < NE; e += 256)
            w2t[c * NE + e] = f2bf(w2[(size_t)e * NC + c]);
    } else if (bid == NE + NC) {
#pragma unroll
        for (int i = 0; i < 3; ++i)
            dcoef[i * NC + tid] = 0.25f * sigm_(dlog[i * NC + tid]);
    } else {                              // gate weights -> bf16, same [k][c] layout
        const int k = bid - (NE + NC + 1);
        wgb[(0 * NC + k) * NC + tid] = f2bf(wf[(size_t)k * NC + tid]);
        wgb[(1 * NC + k) * NC + tid] = f2bf(wi[(size_t)k * NC + tid]);
        wgb[(2 * NC + k) * NC + tid] = f2bf(wc[(size_t)k * NC + tid]);
    }
}

// ---------- prologue: forcing -> bf16 ----------
__global__ void fconv_kernel(const float* __restrict__ fin, ushort* __restrict__ fout) {
    const size_t i8 = ((size_t)blockIdx.x * 256 + threadIdx.x) * 8;
    const float4 a = *reinterpret_cast<const float4*>(fin + i8);
    const float4 b = *reinterpret_cast<const float4*>(fin + i8 + 4);
    uint4 o;
    o.x = (unsigned)f2bf(a.x) | ((unsigned)f2bf(a.y) << 16);
    o.y = (unsigned)f2bf(a.z) | ((unsigned)f2bf(a.w) << 16);
    o.z = (unsigned)f2bf(b.x) | ((unsigned)f2bf(b.y) << 16);
    o.w = (unsigned)f2bf(b.z) | ((unsigned)f2bf(b.w) << 16);
    *reinterpret_cast<uint4*>(fout + i8) = o;
}

// ---------- prologue: initial per-row channel sums from u0 ----------
__global__ __launch_bounds__(256) void rs0_kernel(const float* __restrict__ u,
                                                  float* __restrict__ rowsums) {
    const int b = blockIdx.x >> 6, y = blockIdx.x & 63;
    const int c = threadIdx.x;
    const float* rp = u + ((size_t)b * NC + c) * NHW + (size_t)y * NW;
    float s = 0.f;
#pragma unroll
    for (int i = 0; i < 16; ++i) {
        const float4 v = *reinterpret_cast<const float4*>(rp + i * 4);
        s += (v.x + v.y) + (v.z + v.w);
    }
    rowsums[((size_t)b * 64 + y) * NC + c] = s;
}

// ---------- gated global memory: 3 gates in parallel, bf16 weights ----------
__global__ __launch_bounds__(768) void gates_kernel(
    const float* __restrict__ rowsums, const ushort* __restrict__ wgb,
    const float* __restrict__ bfv, const float* __restrict__ biv,
    const float* __restrict__ bcv,
    float* __restrict__ h, const int first) {
    const int b = blockIdx.x;
    const int tid = threadIdx.x;
    const int g = tid >> 8, c = tid & 255;
    __shared__ float sp[256];
    __shared__ float psum[3][256];
    __shared__ float gf[256], gi[256];
    const int y0 = (g == 0) ? 0 : (g == 1) ? 21 : 42;
    const int y1 = (g == 0) ? 21 : (g == 1) ? 42 : 64;
    const float* rs = rowsums + (size_t)b * 64 * NC + c;
    float s = 0.f;
    for (int y = y0; y < y1; ++y) s += rs[y * NC];
    psum[g][c] = s;
    __syncthreads();
    if (g == 0) sp[c] = (psum[0][c] + psum[1][c] + psum[2][c]) * (1.f / 4096.f);
    __syncthreads();
    const ushort* W16 = wgb + (size_t)g * NC * NC;
    const float* Bv = (g == 0) ? bfv : (g == 1) ? biv : bcv;
    float aA = 0.f, aB = 0.f, aC = 0.f, aD = 0.f;
#pragma unroll 4
    for (int k = 0; k < 256; k += 4) {
        aA = fmaf(sp[k],     bf2f(W16[(k)     * NC + c]), aA);
        aB = fmaf(sp[k + 1], bf2f(W16[(k + 1) * NC + c]), aB);
        aC = fmaf(sp[k + 2], bf2f(W16[(k + 2) * NC + c]), aC);
        aD = fmaf(sp[k + 3], bf2f(W16[(k + 3) * NC + c]), aD);
    }
    const float a = ((aA + aB) + (aC + aD)) + Bv[c];
    if (g == 0) gf[c] = sigm_(a);
    else if (g == 1) gi[c] = sigm_(a);
    __syncthreads();
    if (g == 2) {
        const float cc = tanhf(a);
        const float hold = first ? 0.f : h[b * NC + c];
        h[b * NC + c] = hold * gf[c] + gi[c] * cc;
    }
}

// ---------- fused step: stages Xs from u directly; pipelined 32-wide e-chunks ----------
__global__ __launch_bounds__(512, 4) void step_kernel(
    const ushort* __restrict__ w1t, const ushort* __restrict__ w2t,
    const float* __restrict__ b1, const float* __restrict__ b2,
    const float* __restrict__ uin, const ushort* __restrict__ forc,
    const float* __restrict__ dcoef, const float* __restrict__ hbuf,
    const float* __restrict__ nsc, const float* __restrict__ p_logdt,
    const float* __restrict__ p_am, const float* __restrict__ p_af,
    const int do_norm, float* __restrict__ uout, float* __restrict__ rowsums) {
    __shared__ __align__(16) char pool[75776];
    ushort* Xs  = (ushort*)pool;                 // [64px][256c] swizzled      (32KB)
    ushort* WAu = (ushort*)(pool + 32768);       // w1 chunk [32e][256c] swz   (16KB)
    ushort* WBu = (ushort*)(pool + 49152);       // w2 chunk [256c][32e] swz   (16KB)
    ushort* Hsu = (ushort*)(pool + 65536);       // Hs dbuf 2x[64px][40e-pad]  (10KB)

    const int tid = threadIdx.x;
    const int wv = tid >> 6, lane = tid & 63;
    const int r16 = lane & 15, kg = lane >> 4;
    const int work = (blockIdx.x & 7) * 64 + (blockIdx.x >> 3);   // XCD swizzle
    const int b = work >> 6, y = work & 63;

    const float* ub = uin + (size_t)b * NC * NHW;
    const float* uyb = ub + (size_t)y * NW;

    // ---- stage w1 chunk 0 (gload) + Xs from u row y (reg 4x4 transpose -> ds_write) ----
#pragma unroll
    for (int i = 0; i < 2; ++i) {
        const int idx = i * 512 + tid, row = idx >> 5, s = idx & 31;
        gload16(w1t + (size_t)row * NC + ((s ^ (row & 7)) << 3), WAu + idx * 8);
    }
#pragma unroll
    for (int tt = 0; tt < 2; ++tt) {
        const int id = tt * 512 + tid;
        const int pg_ = id & 15, cg_ = id >> 4;       // cg_ 0..63
        const int px0 = pg_ * 4, c0 = cg_ * 4;
        const float4 r0 = *(const float4*)(uyb + (size_t)(c0 + 0) * NHW + px0);
        const float4 r1 = *(const float4*)(uyb + (size_t)(c0 + 1) * NHW + px0);
        const float4 r2 = *(const float4*)(uyb + (size_t)(c0 + 2) * NHW + px0);
        const float4 r3 = *(const float4*)(uyb + (size_t)(c0 + 3) * NHW + px0);
        const int slot = c0 >> 3, sub = c0 & 7;       // sub in {0,4}
        const float a0[4] = {r0.x, r0.y, r0.z, r0.w};
        const float a1[4] = {r1.x, r1.y, r1.z, r1.w};
        const float a2[4] = {r2.x, r2.y, r2.z, r2.w};
        const float a3[4] = {r3.x, r3.y, r3.z, r3.w};
#pragma unroll
        for (int i2 = 0; i2 < 4; ++i2) {
            const int px = px0 + i2;
            ushort4 xv;
            xv.x = f2bf(a0[i2]);
            xv.y = f2bf(a1[i2]);
            xv.z = f2bf(a2[i2]);
            xv.w = f2bf(a3[i2]);
            *(ushort4*)(Xs + px * 256 + ((slot ^ (px & 7)) << 3) + sub) = xv;
        }
    }

    f32x4 acc2[2][4];   // [ct][p]; wave's c-slice = wv*32
#pragma unroll
    for (int ct = 0; ct < 2; ++ct)
#pragma unroll
        for (int p = 0; p < 4; ++p) acc2[ct][p] = (f32x4){0.f, 0.f, 0.f, 0.f};

    const int eh = wv >> 2, pq = wv & 3;   // GEMM1 wave role: e-half, px-quadrant
    __syncthreads();                       // Xs (ds_write) + WA(0) (gload) ready

    for (int ec = 0; ec < 16; ++ec) {
        // stage w2 chunk ec -> WB: LINEAR dest, inverse-swz SOURCE (rule #21)
#pragma unroll
        for (int i = 0; i < 2; ++i) {
            const int idx = i * 512 + tid, row = idx >> 2, s = idx & 3;
            const int sc = (s ^ ((row >> 1) & 3)) << 3;
            gload16(w2t + (size_t)row * NE + ec * 32 + sc, WBu + idx * 8);
        }
        // GEMM1: D1[e][px] from WA x Xs
        f32x4 acc1 = (f32x4){0.f, 0.f, 0.f, 0.f};
        const int rA = eh * 16 + r16, rB = pq * 16 + r16;
#pragma unroll
        for (int kk = 0; kk < 8; ++kk) {
            const int g = kk * 4 + kg;
            const bfrag8 a = *(const bfrag8*)(WAu + rA * 256 + ((g ^ (rA & 7)) << 3));
            const bfrag8 bb = *(const bfrag8*)(Xs + rB * 256 + ((g ^ (rB & 7)) << 3));
            acc1 = __builtin_amdgcn_mfma_f32_16x16x32_bf16(a, bb, acc1, 0, 0, 0);
        }
        // GELU -> Hs[ec&1]
        ushort* Hc = Hsu + (ec & 1) * 2560;
        {
            const int el = eh * 16 + kg * 4;
            const float4 b1v = *(const float4*)(b1 + ec * 32 + el);
            ushort4 hv;
            hv.x = f2bf(gelu_(acc1[0] + b1v.x));
            hv.y = f2bf(gelu_(acc1[1] + b1v.y));
            hv.z = f2bf(gelu_(acc1[2] + b1v.z));
            hv.w = f2bf(gelu_(acc1[3] + b1v.w));
            *(ushort4*)(Hc + (pq * 16 + r16) * 40 + el) = hv;
        }
        __syncthreads();   // B1: WB drained (hidden under G1+GELU); Hs visible; WA free
        if (ec < 15) {     // stage w1 chunk ec+1 -> WA (drains at B2, hidden under G2)
#pragma unroll
            for (int i = 0; i < 2; ++i) {
                const int idx = i * 512 + tid, row = idx >> 5, s = idx & 31;
                gload16(w1t + (size_t)((ec + 1) * 32 + row) * NC + ((s ^ (row & 7)) << 3),
                        WAu + idx * 8);
            }
        }
        // GEMM2: react[c][px] += WB x Hs
#pragma unroll
        for (int ct = 0; ct < 2; ++ct) {
            const int rowA = wv * 32 + ct * 16 + r16;
            const bfrag8 a2 = *(const bfrag8*)(WBu + rowA * 32 + ((kg ^ ((rowA >> 1) & 3)) << 3));
#pragma unroll
            for (int p = 0; p < 4; ++p) {
                const bfrag8 bf2 = *(const bfrag8*)(Hc + (p * 16 + r16) * 40 + kg * 8);
                acc2[ct][p] = __builtin_amdgcn_mfma_f32_16x16x32_bf16(a2, bf2, acc2[ct][p], 0, 0, 0);
            }
        }
        __syncthreads();   // B2: WA(ec+1) drained; WB free for next stage
    }

    // ---- epilogue ----
    float* trh = (float*)pool;                     // [128][68] f32 (half of c)
    float* su  = (float*)(pool + 34816);           // [128][68] f32 (u_old half)
    const int eg2 = tid >> 4, pg = tid & 15, x0p = pg * 4;
    const float dt = fminf(fmaxf(expf(p_logdt[0]), 0.01f), 0.3f);
    const float am = p_am[0], afc = p_af[0];
    const ushort* frow = forc + (size_t)b * NC * NHW + (size_t)y * NW;

    float unew[2][4][4];   // [h2][jc][ip]

#pragma unroll
    for (int h2 = 0; h2 < 2; ++h2) {
        __syncthreads();   // GEMM done / prev-half trh+su reads done
        if ((wv >> 2) == h2) {
#pragma unroll
            for (int ct = 0; ct < 2; ++ct)
#pragma unroll
                for (int p = 0; p < 4; ++p)
#pragma unroll
                    for (int j = 0; j < 4; ++j)
                        trh[((wv & 3) * 32 + ct * 16 + kg * 4 + j) * 68 + p * 16 + r16] =
                            acc2[ct][p][j];
        }
#pragma unroll
        for (int i = 0; i < 4; ++i) {   // stage u_old half [128c][64px]
            const int idx = i * 512 + tid;
            const int r = idx >> 4, q = (idx & 15) * 4;
            *(float4*)&su[r * 68 + q] =
                *(const float4*)(ub + (size_t)(h2 * 128 + r) * NHW + (size_t)y * NW + q);
        }
        __syncthreads();   // trh + su ready
#pragma unroll
        for (int jc = 0; jc < 4; ++jc) {
            const int crel = eg2 * 4 + jc;
            const int c = h2 * 128 + crel;
            const float co0 = dcoef[c];
            const float co1 = dcoef[NC + c];
            const float co2 = dcoef[2 * NC + c];
            const float hterm = am * hbuf[b * NC + c];
            const float b2v = b2[c];
            const float* up = ub + (size_t)c * NHW;

            float ym[6][4];
            const int dy[6] = {-1, 1, -2, 2, -4, 4};
#pragma unroll
            for (int n = 0; n < 6; ++n) {
                int ry = y + dy[n];
                ry = ry < 0 ? -ry : (ry > 63 ? 126 - ry : ry);
                const float4 t = *reinterpret_cast<const float4*>(up + (size_t)ry * NW + x0p);
                ym[n][0] = t.x; ym[n][1] = t.y; ym[n][2] = t.z; ym[n][3] = t.w;
            }
            const uint2 fr = *reinterpret_cast<const uint2*>(frow + (size_t)c * NHW + x0p);
            float fv[4];
            fv[0] = bf2f((ushort)(fr.x & 0xffff));
            fv[1] = bf2f((ushort)(fr.x >> 16));
            fv[2] = bf2f((ushort)(fr.y & 0xffff));
            fv[3] = bf2f((ushort)(fr.y >> 16));
            const f32x4 rv = *reinterpret_cast<const f32x4*>(&trh[crel * 68 + x0p]);
#pragma unroll
            for (int ip = 0; ip < 4; ++ip) {
                const int x = x0p + ip;
                const float uc = su[crel * 68 + x];
                int xm, xp2;
                float dsum = 0.f, lap;
                xm = x - 1; xm = xm < 0 ? -xm : xm;
                xp2 = x + 1; xp2 = xp2 > 63 ? 126 - xp2 : xp2;
                lap = su[crel * 68 + xm] + su[crel * 68 + xp2] + ym[0][ip] + ym[1][ip] - 4.f * uc;
                dsum = fmaf(co0, lap, dsum);
                xm = x - 2; xm = xm < 0 ? -xm : xm;
                xp2 = x + 2; xp2 = xp2 > 63 ? 126 - xp2 : xp2;
                lap = su[crel * 68 + xm] + su[crel * 68 + xp2] + ym[2][ip] + ym[3][ip] - 4.f * uc;
                dsum = fmaf(co1, lap, dsum);
                xm = x - 4; xm = xm < 0 ? -xm : xm;
                xp2 = x + 4; xp2 = xp2 > 63 ? 126 - xp2 : xp2;
                lap = su[crel * 68 + xm] + su[crel * 68 + xp2] + ym[4][ip] + ym[5][ip] - 4.f * uc;
                dsum = fmaf(co2, lap, dsum);

                const float du_ = dsum + rv[ip] + b2v + hterm + afc * fv[ip];
                unew[h2][jc][ip] = uc + dt * du_;
            }
        }
    }
    __syncthreads();   // trh/su dead

    // ---- RMSNorm ----
    float* redc   = (float*)(pool + 34816);        // [32][68]
    float* inv64p = (float*)(pool + 43520);        // [64]
    if (do_norm) {
        float ps[4] = {0.f, 0.f, 0.f, 0.f};
#pragma unroll
        for (int h2 = 0; h2 < 2; ++h2)
#pragma unroll
            for (int jc = 0; jc < 4; ++jc)
#pragma unroll
                for (int ip = 0; ip < 4; ++ip)
                    ps[ip] = fmaf(unew[h2][jc][ip], unew[h2][jc][ip], ps[ip]);
        *reinterpret_cast<f32x4*>(&redc[eg2 * 68 + x0p]) = (f32x4){ps[0], ps[1], ps[2], ps[3]};
        __syncthreads();
        if (tid < 64) {
            float s = 0.f;
#pragma unroll
            for (int g = 0; g < 32; ++g) s += redc[g * 68 + tid];
            inv64p[tid] = 1.f / (sqrtf(s) * 0.0625f + 1e-6f);
        }
    }
    __syncthreads();   // inv64 ready

    // ---- store u_new (fp32, channel-major) + rowsums ----
    float* sums = (float*)(pool + 52224);          // [256][17]
    float persum[2][4];
    float* uob = uout + (size_t)b * NC * NHW + (size_t)y * NW;
#pragma unroll
    for (int h2 = 0; h2 < 2; ++h2) {
#pragma unroll
        for (int jc = 0; jc < 4; ++jc) {
            const int c = h2 * 128 + eg2 * 4 + jc;
            const float ns = do_norm ? nsc[c] : 1.f;
            float vv[4];
#pragma unroll
            for (int ip = 0; ip < 4; ++ip) {
                float v = unew[h2][jc][ip];
                if (do_norm) v *= inv64p[x0p + ip] * ns;
                vv[ip] = v;
            }
            persum[h2][jc] = (vv[0] + vv[1]) + (vv[2] + vv[3]);
            float4 o; o.x = vv[0]; o.y = vv[1]; o.z = vv[2]; o.w = vv[3];
            *reinterpret_cast<float4*>(uob + (size_t)c * NHW + x0p) = o;
            sums[c * 17 + pg] = persum[h2][jc];
        }
    }
    __syncthreads();   // sums ready
    if (tid < 256) {
        float s = 0.f;
#pragma unroll
        for (int g = 0; g < 16; ++g) s += sums[tid * 17 + g];
        rowsums[((size_t)b * 64 + y) * NC + tid] = s;
    }
}

extern "C" void kernel_launch(void* const* d_in, const int* in_sizes, int n_in,
                              void* d_out, int out_size, void* d_ws, size_t ws_size,
                              hipStream_t stream) {
    (void)in_sizes; (void)n_in; (void)out_size; (void)ws_size;
    const float* u0      = (const float*)d_in[0];
    const float* forcing = (const float*)d_in[1];
    const float* dlog    = (const float*)d_in[2];
    const float* w1      = (const float*)d_in[3];
    const float* b1      = (const float*)d_in[4];
    const float* w2      = (const float*)d_in[5];
    const float* b2      = (const float*)d_in[6];
    const float* wf      = (const float*)d_in[7];
    const float* bfv     = (const float*)d_in[8];
    const float* wi      = (const float*)d_in[9];
    const float* biv     = (const float*)d_in[10];
    const float* wc      = (const float*)d_in[11];
    const float* bcv     = (const float*)d_in[12];
    const float* nsc     = (const float*)d_in[13];
    const float* p_logdt = (const float*)d_in[14];
    const float* p_am    = (const float*)d_in[15];
    const float* p_af    = (const float*)d_in[16];

    float* uout = (float*)d_out;

    char* w = (char*)d_ws;
    float*  uA     = (float*)w;   w += (size_t)NB * NC * NHW * 4;   // 33.5 MB
    ushort* forc   = (ushort*)w;  w += (size_t)NB * NC * NHW * 2;   // 16.8 MB
    ushort* w1t    = (ushort*)w;  w += (size_t)NE * NC * 2;
    ushort* w2t    = (ushort*)w;  w += (size_t)NC * NE * 2;
    ushort* wgb    = (ushort*)w;  w += (size_t)3 * NC * NC * 2;     // 384 KB
    float* rowsums = (float*)w;   w += (size_t)NB * NH * NC * 4;    // 512 KB
    float* hbuf    = (float*)w;   w += (size_t)NB * NC * 4;
    float* dcoef   = (float*)w;   w += (size_t)3 * NC * 4;

    wt_kernel<<<NE + NC + 1 + NC, 256, 0, stream>>>(w1, w2, dlog, wf, wi, wc,
                                                    w1t, w2t, dcoef, wgb);
    fconv_kernel<<<4096, 256, 0, stream>>>(forcing, forc);
    rs0_kernel<<<NB * NH, 256, 0, stream>>>(u0, rowsums);

    const float* src = u0;
    for (int t = 0; t < STEPS; ++t) {
        float* dst = (t & 1) ? uout : uA;    // t=5 -> uout
        gates_kernel<<<NB, 768, 0, stream>>>(rowsums, wgb, bfv, biv, bcv, hbuf, t == 0);
        step_kernel<<<NB * NH, 512, 0, stream>>>(w1t, w2t, b1, b2, src, forc, dcoef,
                                                 hbuf, nsc, p_logdt, p_am, p_af,
                                                 ((t + 1) % 2) == 0, dst, rowsums);
        src = dst;
    }
}

// Round 15
// 553.371 us; speedup vs baseline: 1.0586x; 1.0215x over previous
//
#include <hip/hip_runtime.h>
#include <math.h>

constexpr int NB = 8, NC = 256, NE = 512, NH = 64, NW = 64, NHW = NH * NW;
constexpr int STEPS = 6;

typedef short bfrag8 __attribute__((ext_vector_type(8)));   // 8 bf16 in 4 VGPRs
typedef float f32x4 __attribute__((ext_vector_type(4)));

__device__ __forceinline__ float sigm_(float x) { return 1.f / (1.f + expf(-x)); }
// tanh-form GELU, overflow-safe: x * sigmoid(1.5957691(x + 0.044715 x^3))
__device__ __forceinline__ float gelu_(float x) {
    const float t2 = fmaf(0.0713548162f * x, x * x, 1.5957691216f * x);
    return x / (1.f + __expf(-t2));
}
__device__ __forceinline__ ushort f2bf(float f) {
    unsigned u = __builtin_bit_cast(unsigned, f);
    unsigned r = (u + 0x7fffu + ((u >> 16) & 1u)) >> 16;   // RNE
    return (ushort)r;
}
__device__ __forceinline__ float bf2f(ushort us) {
    return __builtin_bit_cast(float, (unsigned)us << 16);
}
__device__ __forceinline__ void gload16(const void* g, void* l) {
    __builtin_amdgcn_global_load_lds((const __attribute__((address_space(1))) void*)g,
                                     (__attribute__((address_space(3))) void*)l, 16, 0, 0);
}

// ---------- prologue: bf16 weights (w1t, w2t, gates) + stencil coefficients ----------
__global__ void wt_kernel(const float* __restrict__ w1, const float* __restrict__ w2,
                          const float* __restrict__ dlog,
                          const float* __restrict__ wf, const float* __restrict__ wi,
                          const float* __restrict__ wc,
                          ushort* __restrict__ w1t, ushort* __restrict__ w2t,
                          float* __restrict__ dcoef, ushort* __restrict__ wgb) {
    const int bid = blockIdx.x, tid = threadIdx.x;
    if (bid < NE) {                       // w1t[e][c] = w1[c][e]
        w1t[bid * NC + tid] = f2bf(w1[(size_t)tid * NE + bid]);
    } else if (bid < NE + NC) {           // w2t[c][e] = w2[e][c]
        const int c = bid - NE;
        for (int e = tid; e < NE; e += 256)
            w2t[c * NE + e] = f2bf(w2[(size_t)e * NC + c]);
    } else if (bid == NE + NC) {
#pragma unroll
        for (int i = 0; i < 3; ++i)
            dcoef[i * NC + tid] = 0.25f * sigm_(dlog[i * NC + tid]);
    } else {                              // gate weights -> bf16, same [k][c] layout
        const int k = bid - (NE + NC + 1);
        wgb[(0 * NC + k) * NC + tid] = f2bf(wf[(size_t)k * NC + tid]);
        wgb[(1 * NC + k) * NC + tid] = f2bf(wi[(size_t)k * NC + tid]);
        wgb[(2 * NC + k) * NC + tid] = f2bf(wc[(size_t)k * NC + tid]);
    }
}

// ---------- prologue: forcing -> bf16 ----------
__global__ void fconv_kernel(const float* __restrict__ fin, ushort* __restrict__ fout) {
    const size_t i8 = ((size_t)blockIdx.x * 256 + threadIdx.x) * 8;
    const float4 a = *reinterpret_cast<const float4*>(fin + i8);
    const float4 b = *reinterpret_cast<const float4*>(fin + i8 + 4);
    uint4 o;
    o.x = (unsigned)f2bf(a.x) | ((unsigned)f2bf(a.y) << 16);
    o.y = (unsigned)f2bf(a.z) | ((unsigned)f2bf(a.w) << 16);
    o.z = (unsigned)f2bf(b.x) | ((unsigned)f2bf(b.y) << 16);
    o.w = (unsigned)f2bf(b.z) | ((unsigned)f2bf(b.w) << 16);
    *reinterpret_cast<uint4*>(fout + i8) = o;
}

// ---------- prologue: initial per-row channel sums from u0 ----------
__global__ __launch_bounds__(256) void rs0_kernel(const float* __restrict__ u,
                                                  float* __restrict__ rowsums) {
    const int b = blockIdx.x >> 6, y = blockIdx.x & 63;
    const int c = threadIdx.x;
    const float* rp = u + ((size_t)b * NC + c) * NHW + (size_t)y * NW;
    float s = 0.f;
#pragma unroll
    for (int i = 0; i < 16; ++i) {
        const float4 v = *reinterpret_cast<const float4*>(rp + i * 4);
        s += (v.x + v.y) + (v.z + v.w);
    }
    rowsums[((size_t)b * 64 + y) * NC + c] = s;
}

// ---------- gated global memory: 3 gates in parallel, bf16 weights ----------
__global__ __launch_bounds__(768) void gates_kernel(
    const float* __restrict__ rowsums, const ushort* __restrict__ wgb,
    const float* __restrict__ bfv, const float* __restrict__ biv,
    const float* __restrict__ bcv,
    float* __restrict__ h, const int first) {
    const int b = blockIdx.x;
    const int tid = threadIdx.x;
    const int g = tid >> 8, c = tid & 255;
    __shared__ float sp[256];
    __shared__ float psum[3][256];
    __shared__ float gf[256], gi[256];
    const int y0 = (g == 0) ? 0 : (g == 1) ? 21 : 42;
    const int y1 = (g == 0) ? 21 : (g == 1) ? 42 : 64;
    const float* rs = rowsums + (size_t)b * 64 * NC + c;
    float s = 0.f;
    for (int y = y0; y < y1; ++y) s += rs[y * NC];
    psum[g][c] = s;
    __syncthreads();
    if (g == 0) sp[c] = (psum[0][c] + psum[1][c] + psum[2][c]) * (1.f / 4096.f);
    __syncthreads();
    const ushort* W16 = wgb + (size_t)g * NC * NC;
    const float* Bv = (g == 0) ? bfv : (g == 1) ? biv : bcv;
    float aA = 0.f, aB = 0.f, aC = 0.f, aD = 0.f;
#pragma unroll 4
    for (int k = 0; k < 256; k += 4) {
        aA = fmaf(sp[k],     bf2f(W16[(k)     * NC + c]), aA);
        aB = fmaf(sp[k + 1], bf2f(W16[(k + 1) * NC + c]), aB);
        aC = fmaf(sp[k + 2], bf2f(W16[(k + 2) * NC + c]), aC);
        aD = fmaf(sp[k + 3], bf2f(W16[(k + 3) * NC + c]), aD);
    }
    const float a = ((aA + aB) + (aC + aD)) + Bv[c];
    if (g == 0) gf[c] = sigm_(a);
    else if (g == 1) gi[c] = sigm_(a);
    __syncthreads();
    if (g == 2) {
        const float cc = tanhf(a);
        const float hold = first ? 0.f : h[b * NC + c];
        h[b * NC + c] = hold * gf[c] + gi[c] * cc;
    }
}

// ---------- fused step: r14 GEMM body + reflect-window stencil epilogue ----------
__global__ __launch_bounds__(512, 4) void step_kernel(
    const ushort* __restrict__ w1t, const ushort* __restrict__ w2t,
    const float* __restrict__ b1, const float* __restrict__ b2,
    const float* __restrict__ uin, const ushort* __restrict__ forc,
    const float* __restrict__ dcoef, const float* __restrict__ hbuf,
    const float* __restrict__ nsc, const float* __restrict__ p_logdt,
    const float* __restrict__ p_am, const float* __restrict__ p_af,
    const int do_norm, float* __restrict__ uout, float* __restrict__ rowsums) {
    __shared__ __align__(16) char pool[75776];
    ushort* Xs  = (ushort*)pool;                 // [64px][256c] swizzled      (32KB)
    ushort* WAu = (ushort*)(pool + 32768);       // w1 chunk [32e][256c] swz   (16KB)
    ushort* WBu = (ushort*)(pool + 49152);       // w2 chunk [256c][32e] swz   (16KB)
    ushort* Hsu = (ushort*)(pool + 65536);       // Hs dbuf 2x[64px][40e-pad]  (10KB)

    const int tid = threadIdx.x;
    const int wv = tid >> 6, lane = tid & 63;
    const int r16 = lane & 15, kg = lane >> 4;
    const int work = (blockIdx.x & 7) * 64 + (blockIdx.x >> 3);   // XCD swizzle
    const int b = work >> 6, y = work & 63;

    const float* ub = uin + (size_t)b * NC * NHW;
    const float* uyb = ub + (size_t)y * NW;

    // ---- stage w1 chunk 0 (gload) + Xs from u row y (reg 4x4 transpose -> ds_write) ----
#pragma unroll
    for (int i = 0; i < 2; ++i) {
        const int idx = i * 512 + tid, row = idx >> 5, s = idx & 31;
        gload16(w1t + (size_t)row * NC + ((s ^ (row & 7)) << 3), WAu + idx * 8);
    }
#pragma unroll
    for (int tt = 0; tt < 2; ++tt) {
        const int id = tt * 512 + tid;
        const int pg_ = id & 15, cg_ = id >> 4;       // cg_ 0..63
        const int px0 = pg_ * 4, c0 = cg_ * 4;
        const float4 r0 = *(const float4*)(uyb + (size_t)(c0 + 0) * NHW + px0);
        const float4 r1 = *(const float4*)(uyb + (size_t)(c0 + 1) * NHW + px0);
        const float4 r2 = *(const float4*)(uyb + (size_t)(c0 + 2) * NHW + px0);
        const float4 r3 = *(const float4*)(uyb + (size_t)(c0 + 3) * NHW + px0);
        const int slot = c0 >> 3, sub = c0 & 7;       // sub in {0,4}
        const float a0[4] = {r0.x, r0.y, r0.z, r0.w};
        const float a1[4] = {r1.x, r1.y, r1.z, r1.w};
        const float a2[4] = {r2.x, r2.y, r2.z, r2.w};
        const float a3[4] = {r3.x, r3.y, r3.z, r3.w};
#pragma unroll
        for (int i2 = 0; i2 < 4; ++i2) {
            const int px = px0 + i2;
            ushort4 xv;
            xv.x = f2bf(a0[i2]);
            xv.y = f2bf(a1[i2]);
            xv.z = f2bf(a2[i2]);
            xv.w = f2bf(a3[i2]);
            *(ushort4*)(Xs + px * 256 + ((slot ^ (px & 7)) << 3) + sub) = xv;
        }
    }

    f32x4 acc2[2][4];   // [ct][p]; wave's c-slice = wv*32
#pragma unroll
    for (int ct = 0; ct < 2; ++ct)
#pragma unroll
        for (int p = 0; p < 4; ++p) acc2[ct][p] = (f32x4){0.f, 0.f, 0.f, 0.f};

    const int eh = wv >> 2, pq = wv & 3;   // GEMM1 wave role: e-half, px-quadrant
    __syncthreads();                       // Xs (ds_write) + WA(0) (gload) ready

    for (int ec = 0; ec < 16; ++ec) {
        // stage w2 chunk ec -> WB: LINEAR dest, inverse-swz SOURCE (rule #21)
#pragma unroll
        for (int i = 0; i < 2; ++i) {
            const int idx = i * 512 + tid, row = idx >> 2, s = idx & 3;
            const int sc = (s ^ ((row >> 1) & 3)) << 3;
            gload16(w2t + (size_t)row * NE + ec * 32 + sc, WBu + idx * 8);
        }
        // GEMM1: D1[e][px] from WA x Xs
        f32x4 acc1 = (f32x4){0.f, 0.f, 0.f, 0.f};
        const int rA = eh * 16 + r16, rB = pq * 16 + r16;
#pragma unroll
        for (int kk = 0; kk < 8; ++kk) {
            const int g = kk * 4 + kg;
            const bfrag8 a = *(const bfrag8*)(WAu + rA * 256 + ((g ^ (rA & 7)) << 3));
            const bfrag8 bb = *(const bfrag8*)(Xs + rB * 256 + ((g ^ (rB & 7)) << 3));
            acc1 = __builtin_amdgcn_mfma_f32_16x16x32_bf16(a, bb, acc1, 0, 0, 0);
        }
        // GELU -> Hs[ec&1]
        ushort* Hc = Hsu + (ec & 1) * 2560;
        {
            const int el = eh * 16 + kg * 4;
            const float4 b1v = *(const float4*)(b1 + ec * 32 + el);
            ushort4 hv;
            hv.x = f2bf(gelu_(acc1[0] + b1v.x));
            hv.y = f2bf(gelu_(acc1[1] + b1v.y));
            hv.z = f2bf(gelu_(acc1[2] + b1v.z));
            hv.w = f2bf(gelu_(acc1[3] + b1v.w));
            *(ushort4*)(Hc + (pq * 16 + r16) * 40 + el) = hv;
        }
        __syncthreads();   // B1: WB drained (hidden under G1+GELU); Hs visible; WA free
        if (ec < 15) {     // stage w1 chunk ec+1 -> WA (drains at B2, hidden under G2)
#pragma unroll
            for (int i = 0; i < 2; ++i) {
                const int idx = i * 512 + tid, row = idx >> 5, s = idx & 31;
                gload16(w1t + (size_t)((ec + 1) * 32 + row) * NC + ((s ^ (row & 7)) << 3),
                        WAu + idx * 8);
            }
        }
        // GEMM2: react[c][px] += WB x Hs
#pragma unroll
        for (int ct = 0; ct < 2; ++ct) {
            const int rowA = wv * 32 + ct * 16 + r16;
            const bfrag8 a2 = *(const bfrag8*)(WBu + rowA * 32 + ((kg ^ ((rowA >> 1) & 3)) << 3));
#pragma unroll
            for (int p = 0; p < 4; ++p) {
                const bfrag8 bf2 = *(const bfrag8*)(Hc + (p * 16 + r16) * 40 + kg * 8);
                acc2[ct][p] = __builtin_amdgcn_mfma_f32_16x16x32_bf16(a2, bf2, acc2[ct][p], 0, 0, 0);
            }
        }
        __syncthreads();   // B2: WA(ec+1) drained; WB free for next stage
    }

    // ---- epilogue: reflect-padded window stencil (r11-verified) ----
    float* trh = (float*)pool;                     // [128][68] f32 @0       (34816 B)
    float* su  = (float*)(pool + 34816);           // [128][72] f32, data at cols 4..67
    const int eg2 = tid >> 4, pg = tid & 15, x0p = pg * 4;
    const float dt = fminf(fmaxf(expf(p_logdt[0]), 0.01f), 0.3f);
    const float am = p_am[0], afc = p_af[0];
    const ushort* frow = forc + (size_t)b * NC * NHW + (size_t)y * NW;

    float unew[2][4][4];   // [h2][jc][ip]

#pragma unroll
    for (int h2 = 0; h2 < 2; ++h2) {
        __syncthreads();   // GEMM done / prev-half trh+su reads done
        if ((wv >> 2) == h2) {
#pragma unroll
            for (int ct = 0; ct < 2; ++ct)
#pragma unroll
                for (int p = 0; p < 4; ++p)
#pragma unroll
                    for (int j = 0; j < 4; ++j)
                        trh[((wv & 3) * 32 + ct * 16 + kg * 4 + j) * 68 + p * 16 + r16] =
                            acc2[ct][p][j];
        }
#pragma unroll
        for (int i = 0; i < 4; ++i) {   // stage u_old half [128c][64px] at col offset 4
            const int idx = i * 512 + tid;
            const int r = idx >> 4, q = (idx & 15) * 4;
            *(float4*)&su[r * 72 + 4 + q] =
                *(const float4*)(ub + (size_t)(h2 * 128 + r) * NHW + (size_t)y * NW + q);
        }
        if (tid < 256) {                 // fill reflect pads from global (L1-hot row)
            const int r = tid >> 1, side = tid & 1;
            const float* gp = ub + (size_t)(h2 * 128 + r) * NHW + (size_t)y * NW;
            float* sr = &su[r * 72];
            if (side == 0) { sr[0] = gp[4]; sr[1] = gp[3]; sr[2] = gp[2]; sr[3] = gp[1]; }
            else { sr[68] = gp[62]; sr[69] = gp[61]; sr[70] = gp[60]; sr[71] = gp[59]; }
        }
        __syncthreads();   // trh + su(+pads) ready
#pragma unroll
        for (int jc = 0; jc < 4; ++jc) {
            const int crel = eg2 * 4 + jc;
            const int c = h2 * 128 + crel;
            const float co0 = dcoef[c];
            const float co1 = dcoef[NC + c];
            const float co2 = dcoef[2 * NC + c];
            const float hterm = am * hbuf[b * NC + c];
            const float b2v = b2[c];
            const float* up = ub + (size_t)c * NHW;

            float ym[6][4];
            const int dy[6] = {-1, 1, -2, 2, -4, 4};
#pragma unroll
            for (int n = 0; n < 6; ++n) {
                int ry = y + dy[n];
                ry = ry < 0 ? -ry : (ry > 63 ? 126 - ry : ry);
                const float4 t = *reinterpret_cast<const float4*>(up + (size_t)ry * NW + x0p);
                ym[n][0] = t.x; ym[n][1] = t.y; ym[n][2] = t.z; ym[n][3] = t.w;
            }
            const uint2 fr = *reinterpret_cast<const uint2*>(frow + (size_t)c * NHW + x0p);
            float fv[4];
            fv[0] = bf2f((ushort)(fr.x & 0xffff));
            fv[1] = bf2f((ushort)(fr.x >> 16));
            fv[2] = bf2f((ushort)(fr.y & 0xffff));
            fv[3] = bf2f((ushort)(fr.y >> 16));
            const f32x4 rv = *reinterpret_cast<const f32x4*>(&trh[crel * 68 + x0p]);
            // 12-float reflect window: w[k] = v[x0p-4+k], v = reflected row
            const f32x4 wm  = *reinterpret_cast<const f32x4*>(&su[crel * 72 + x0p]);
            const f32x4 wc4 = *reinterpret_cast<const f32x4*>(&su[crel * 72 + 4 + x0p]);
            const f32x4 wp  = *reinterpret_cast<const f32x4*>(&su[crel * 72 + 8 + x0p]);
            const float w[12] = {wm[0], wm[1], wm[2], wm[3],
                                 wc4[0], wc4[1], wc4[2], wc4[3],
                                 wp[0], wp[1], wp[2], wp[3]};
#pragma unroll
            for (int ip = 0; ip < 4; ++ip) {
                const float uc = w[4 + ip];
                float dsum;
                float lap = (w[3 + ip] + w[5 + ip]) + (ym[0][ip] + ym[1][ip]) - 4.f * uc;
                dsum = co0 * lap;
                lap = (w[2 + ip] + w[6 + ip]) + (ym[2][ip] + ym[3][ip]) - 4.f * uc;
                dsum = fmaf(co1, lap, dsum);
                lap = (w[ip] + w[8 + ip]) + (ym[4][ip] + ym[5][ip]) - 4.f * uc;
                dsum = fmaf(co2, lap, dsum);

                const float du_ = dsum + rv[ip] + b2v + hterm + afc * fv[ip];
                unew[h2][jc][ip] = uc + dt * du_;
            }
        }
    }
    __syncthreads();   // trh/su dead

    // ---- RMSNorm ----
    float* redc   = (float*)(pool + 34816);        // [32][68] (overlays su front)
    float* inv64p = (float*)(pool + 71680);        // [64] (after su region)
    if (do_norm) {
        float ps[4] = {0.f, 0.f, 0.f, 0.f};
#pragma unroll
        for (int h2 = 0; h2 < 2; ++h2)
#pragma unroll
            for (int jc = 0; jc < 4; ++jc)
#pragma unroll
                for (int ip = 0; ip < 4; ++ip)
                    ps[ip] = fmaf(unew[h2][jc][ip], unew[h2][jc][ip], ps[ip]);
        *reinterpret_cast<f32x4*>(&redc[eg2 * 68 + x0p]) = (f32x4){ps[0], ps[1], ps[2], ps[3]};
        __syncthreads();
        if (tid < 64) {
            float s = 0.f;
#pragma unroll
            for (int g = 0; g < 32; ++g) s += redc[g * 68 + tid];
            inv64p[tid] = 1.f / (sqrtf(s) * 0.0625f + 1e-6f);
        }
    }
    __syncthreads();   // inv64 ready; redc dead

    // ---- store u_new (fp32, channel-major) + rowsums ----
    float* sums = (float*)(pool + 43520);          // [256][17] (after redc, before inv64p)
    float persum[2][4];
    float* uob = uout + (size_t)b * NC * NHW + (size_t)y * NW;
#pragma unroll
    for (int h2 = 0; h2 < 2; ++h2) {
#pragma unroll
        for (int jc = 0; jc < 4; ++jc) {
            const int c = h2 * 128 + eg2 * 4 + jc;
            const float ns = do_norm ? nsc[c] : 1.f;
            float vv[4];
#pragma unroll
            for (int ip = 0; ip < 4; ++ip) {
                float v = unew[h2][jc][ip];
                if (do_norm) v *= inv64p[x0p + ip] * ns;
                vv[ip] = v;
            }
            persum[h2][jc] = (vv[0] + vv[1]) + (vv[2] + vv[3]);
            float4 o; o.x = vv[0]; o.y = vv[1]; o.z = vv[2]; o.w = vv[3];
            *reinterpret_cast<float4*>(uob + (size_t)c * NHW + x0p) = o;
            sums[c * 17 + pg] = persum[h2][jc];
        }
    }
    __syncthreads();   // sums ready
    if (tid < 256) {
        float s = 0.f;
#pragma unroll
        for (int g = 0; g < 16; ++g) s += sums[tid * 17 + g];
        rowsums[((size_t)b * 64 + y) * NC + tid] = s;
    }
}

extern "C" void kernel_launch(void* const* d_in, const int* in_sizes, int n_in,
                              void* d_out, int out_size, void* d_ws, size_t ws_size,
                              hipStream_t stream) {
    (void)in_sizes; (void)n_in; (void)out_size; (void)ws_size;
    const float* u0      = (const float*)d_in[0];
    const float* forcing = (const float*)d_in[1];
    const float* dlog    = (const float*)d_in[2];
    const float* w1      = (const float*)d_in[3];
    const float* b1      = (const float*)d_in[4];
    const float* w2      = (const float*)d_in[5];
    const float* b2      = (const float*)d_in[6];
    const float* wf      = (const float*)d_in[7];
    const float* bfv     = (const float*)d_in[8];
    const float* wi      = (const float*)d_in[9];
    const float* biv     = (const float*)d_in[10];
    const float* wc      = (const float*)d_in[11];
    const float* bcv     = (const float*)d_in[12];
    const float* nsc     = (const float*)d_in[13];
    const float* p_logdt = (const float*)d_in[14];
    const float* p_am    = (const float*)d_in[15];
    const float* p_af    = (const float*)d_in[16];

    float* uout = (float*)d_out;

    char* w = (char*)d_ws;
    float*  uA     = (float*)w;   w += (size_t)NB * NC * NHW * 4;   // 33.5 MB
    ushort* forc   = (ushort*)w;  w += (size_t)NB * NC * NHW * 2;   // 16.8 MB
    ushort* w1t    = (ushort*)w;  w += (size_t)NE * NC * 2;
    ushort* w2t    = (ushort*)w;  w += (size_t)NC * NE * 2;
    ushort* wgb    = (ushort*)w;  w += (size_t)3 * NC * NC * 2;     // 384 KB
    float* rowsums = (float*)w;   w += (size_t)NB * NH * NC * 4;    // 512 KB
    float* hbuf    = (float*)w;   w += (size_t)NB * NC * 4;
    float* dcoef   = (float*)w;   w += (size_t)3 * NC * 4;

    wt_kernel<<<NE + NC + 1 + NC, 256, 0, stream>>>(w1, w2, dlog, wf, wi, wc,
                                                    w1t, w2t, dcoef, wgb);
    fconv_kernel<<<4096, 256, 0, stream>>>(forcing, forc);
    rs0_kernel<<<NB * NH, 256, 0, stream>>>(u0, rowsums);

    const float* src = u0;
    for (int t = 0; t < STEPS; ++t) {
        float* dst = (t & 1) ? uout : uA;    // t=5 -> uout
        gates_kernel<<<NB, 768, 0, stream>>>(rowsums, wgb, bfv, biv, bcv, hbuf, t == 0);
        step_kernel<<<NB * NH, 512, 0, stream>>>(w1t, w2t, b1, b2, src, forc, dcoef,
                                                 hbuf, nsc, p_logdt, p_am, p_af,
                                                 ((t + 1) % 2) == 0, dst, rowsums);
        src = dst;
    }
}